// Round 1
// baseline (474.922 us; speedup 1.0000x reference)
//
#include <hip/hip_runtime.h>
#include <hip/hip_bf16.h>

// GQA attention block: x@wq/wk/wv -> RoPE -> causal GQA flash attn -> @wo
// B=2 T=2048 D=2048 H=16 HK=4 HD=128. All GEMMs bf16 MFMA 16x16x32, f32 accum.

constexpr int BB  = 2;
constexpr int TT  = 2048;
constexpr int DD  = 2048;
constexpr int NHD = 16;    // H
constexpr int NKV = 4;     // HK
constexpr int HDD = 128;   // HD
constexpr int MM  = BB * TT;          // 4096 rows for all GEMMs
constexpr int NQ  = NHD * HDD;        // 2048
constexpr int NK  = NKV * HDD;        // 512
constexpr int KK  = DD;               // 2048 (K dim for all GEMMs)

typedef float  f32x4  __attribute__((ext_vector_type(4)));
typedef __bf16 bf16x8 __attribute__((ext_vector_type(8)));
typedef __bf16 bf16x4 __attribute__((ext_vector_type(4)));

__device__ __forceinline__ void async16(const void* g, void* l) {
  __builtin_amdgcn_global_load_lds(
      (const __attribute__((address_space(1))) unsigned int*)g,
      (__attribute__((address_space(3))) unsigned int*)l, 16, 0, 0);
}

// ---------------- elementwise f32 -> bf16 ----------------
__global__ __launch_bounds__(256) void k_cvt(const float* __restrict__ in,
                                             __bf16* __restrict__ out, int n) {
  int idx = (blockIdx.x * blockDim.x + threadIdx.x) * 4;
  int stride = gridDim.x * blockDim.x * 4;
  for (int i = idx; i < n; i += stride) {
    float4 v = *(const float4*)(in + i);
    bf16x4 o;
    o.x = (__bf16)v.x; o.y = (__bf16)v.y; o.z = (__bf16)v.z; o.w = (__bf16)v.w;
    *(bf16x4*)(out + i) = o;
  }
}

// ---------------- (K,N) f32 -> (N,K) bf16 transpose ----------------
__global__ __launch_bounds__(256) void k_transpose_cvt(const float* __restrict__ in,
                                                       __bf16* __restrict__ out,
                                                       int K, int N) {
  __shared__ float tile[32][33];
  int n0 = blockIdx.x * 32, k0 = blockIdx.y * 32;
  int tx = threadIdx.x, ty = threadIdx.y;
#pragma unroll
  for (int i = 0; i < 4; ++i)
    tile[ty + i * 8][tx] = in[(size_t)(k0 + ty + i * 8) * N + n0 + tx];
  __syncthreads();
#pragma unroll
  for (int i = 0; i < 4; ++i)
    out[(size_t)(n0 + ty + i * 8) * K + k0 + tx] = (__bf16)tile[tx][ty + i * 8];
}

// ---------------- GEMM: A(M,K) bf16 row-major  x  BT(N,K) bf16 row-major ----------------
// 128x128 tile, BK=64, 4 waves (2x2 of 64x64), mfma 16x16x32, XOR-swizzled LDS,
// global_load_lds width-16 staging. Epilogue variants fused.
enum { EPI_ROPE_Q = 0, EPI_ROPE_K = 1, EPI_VT = 2, EPI_F32 = 3 };

template <int EPI>
__global__ __launch_bounds__(256, 2)
void k_gemm(const __bf16* __restrict__ A, const __bf16* __restrict__ BT,
            void* __restrict__ Cout, int N,
            const float* __restrict__ fcos, const float* __restrict__ fsin) {
  __shared__ __bf16 sA[128 * 64];
  __shared__ __bf16 sB[128 * 64];
  const int tid = threadIdx.x, wave = tid >> 6, lane = tid & 63;
  const int m0 = blockIdx.y * 128, n0 = blockIdx.x * 128;
  const int r = lane & 15, g = lane >> 4;
  const int wm = (wave >> 1) * 64, wn = (wave & 1) * 64;
  const int srow = lane >> 3;                 // row within 8-row stage block
  const int schunk = (lane & 7) ^ (srow & 7); // pre-swizzled source 16B chunk

  f32x4 acc[4][4] = {};

  const __bf16* aBase = A + (size_t)m0 * KK + schunk * 8;
  const __bf16* bBase = BT + (size_t)n0 * KK + schunk * 8;

  for (int kt = 0; kt < KK; kt += 64) {
#pragma unroll
    for (int i = 0; i < 4; ++i) {
      int t = wave * 4 + i;
      int row = t * 8 + srow;
      async16(aBase + (size_t)row * KK + kt, (char*)sA + t * 1024);
      async16(bBase + (size_t)row * KK + kt, (char*)sB + t * 1024);
    }
    __syncthreads();
    bf16x8 af[4][2], bfr[4][2];
#pragma unroll
    for (int i = 0; i < 4; ++i) {
#pragma unroll
      for (int h = 0; h < 2; ++h) {
        int pc = (h * 4 + g) ^ (r & 7);
        af[i][h]  = *(const bf16x8*)((const char*)sA + (wm + i * 16 + r) * 128 + pc * 16);
        bfr[i][h] = *(const bf16x8*)((const char*)sB + (wn + i * 16 + r) * 128 + pc * 16);
      }
    }
#pragma unroll
    for (int i = 0; i < 4; ++i)
#pragma unroll
      for (int j = 0; j < 4; ++j) {
        acc[i][j] = __builtin_amdgcn_mfma_f32_16x16x32_bf16(af[i][0], bfr[j][0], acc[i][j], 0, 0, 0);
        acc[i][j] = __builtin_amdgcn_mfma_f32_16x16x32_bf16(af[i][1], bfr[j][1], acc[i][j], 0, 0, 0);
      }
    __syncthreads();
  }

  // epilogue: D elem (i,j,jj): row = m0+wm+i*16+g*4+jj, col = n0+wn+j*16+r
#pragma unroll
  for (int i = 0; i < 4; ++i) {
#pragma unroll
    for (int j = 0; j < 4; ++j) {
#pragma unroll
      for (int jj = 0; jj < 4; ++jj) {
        int rm = m0 + wm + i * 16 + g * 4 + jj;
        int cn = n0 + wn + j * 16 + r;
        float v = acc[i][j][jj];
        if constexpr (EPI == EPI_F32) {
          ((float*)Cout)[(size_t)rm * 2048 + cn] = v;
        } else if constexpr (EPI == EPI_VT) {
          int b = rm >> 11, t = rm & (TT - 1);
          int h = cn >> 7, hd = cn & 127;
          ((__bf16*)Cout)[((size_t)(b * NKV + h) * HDD + hd) * TT + t] = (__bf16)v;
        } else {
          float pv = __shfl_xor(v, 1);
          int b = rm >> 11, t = rm & (TT - 1);
          int h = cn >> 7, hd = cn & 127;
          float c = fcos[t * 64 + (hd >> 1)];
          float s = fsin[t * 64 + (hd >> 1)];
          float ov = (hd & 1) ? (pv * s + v * c) : (v * c - pv * s);
          constexpr int HHN = (EPI == EPI_ROPE_Q) ? NHD : NKV;
          ((__bf16*)Cout)[((size_t)(b * HHN + h) * TT + t) * HDD + hd] = (__bf16)ov;
        }
      }
    }
  }
}

// ---------------- flash attention ----------------
// grid (T/64, H, B), 256 thr = 4 waves, wave w owns q rows [q0+16w, +16).
// K tile 64x128 (swz16), VT tile 128x64 (swz8), per-wave P bounce 16x64 (swz8).
__global__ __launch_bounds__(256, 2)
void k_attn(const __bf16* __restrict__ Q, const __bf16* __restrict__ Kc,
            const __bf16* __restrict__ VT, __bf16* __restrict__ Out) {
  __shared__ __bf16 sK[64 * 128];
  __shared__ __bf16 sV[128 * 64];
  __shared__ __bf16 sP[4][16 * 64];

  const int tid = threadIdx.x, wave = tid >> 6, lane = tid & 63;
  const int q0 = blockIdx.x * 64;
  const int h = blockIdx.y, b = blockIdx.z;
  const int kvh = h >> 2;
  const int r = lane & 15, g = lane >> 4;

  const __bf16* Qp = Q + ((size_t)(b * NHD + h) * TT) * HDD;
  const __bf16* Kp = Kc + ((size_t)(b * NKV + kvh) * TT) * HDD;
  const __bf16* Vp = VT + ((size_t)(b * NKV + kvh) * HDD) * TT;

  bf16x8 qf[4];
#pragma unroll
  for (int kh = 0; kh < 4; ++kh)
    qf[kh] = *(const bf16x8*)(Qp + (size_t)(q0 + wave * 16 + r) * HDD + kh * 32 + g * 8);

  f32x4 o[8] = {};
  float mrun[4], lrun[4];
#pragma unroll
  for (int jj = 0; jj < 4; ++jj) { mrun[jj] = -1e30f; lrun[jj] = 0.f; }

  const int nt = q0 / 64 + 1;
  for (int it = 0; it < nt; ++it) {
    const int kv0 = it * 64;
#pragma unroll
    for (int i = 0; i < 4; ++i) {
      int ti = wave * 4 + i;
      int rowk = ti * 4 + (lane >> 4);
      int sck = (lane & 15) ^ (rowk & 15);
      async16(Kp + (size_t)(kv0 + rowk) * HDD + sck * 8, (char*)sK + ti * 1024);
      int rowv = ti * 8 + (lane >> 3);
      int scv = (lane & 7) ^ (rowv & 7);
      async16(Vp + (size_t)rowv * TT + kv0 + scv * 8, (char*)sV + ti * 1024);
    }
    __syncthreads();

    // S = Q K^T (16x64 per wave)
    f32x4 sa[4] = {};
#pragma unroll
    for (int nf = 0; nf < 4; ++nf) {
#pragma unroll
      for (int kh = 0; kh < 4; ++kh) {
        int row = nf * 16 + r;
        int pc = (kh * 4 + g) ^ (row & 15);
        bf16x8 kf = *(const bf16x8*)((const char*)sK + row * 256 + pc * 16);
        sa[nf] = __builtin_amdgcn_mfma_f32_16x16x32_bf16(qf[kh], kf, sa[nf], 0, 0, 0);
      }
    }
    const float SC = 0.08838834764831845f; // 1/sqrt(128)
    const bool diag = (kv0 == q0);
#pragma unroll
    for (int nf = 0; nf < 4; ++nf)
#pragma unroll
      for (int jj = 0; jj < 4; ++jj) {
        float s = sa[nf][jj] * SC;
        if (diag) {
          int row = q0 + wave * 16 + g * 4 + jj;
          int col = kv0 + nf * 16 + r;
          if (col > row) s = -1e30f;
        }
        sa[nf][jj] = s;
      }
    // online softmax per row (row = wave*16 + g*4 + jj, spread over 16 lanes)
    float mnew[4], scf[4], tsum[4];
#pragma unroll
    for (int jj = 0; jj < 4; ++jj) {
      float mx = fmaxf(fmaxf(sa[0][jj], sa[1][jj]), fmaxf(sa[2][jj], sa[3][jj]));
      mx = fmaxf(mx, __shfl_xor(mx, 1));
      mx = fmaxf(mx, __shfl_xor(mx, 2));
      mx = fmaxf(mx, __shfl_xor(mx, 4));
      mx = fmaxf(mx, __shfl_xor(mx, 8));
      mnew[jj] = fmaxf(mrun[jj], mx);
      scf[jj] = __expf(mrun[jj] - mnew[jj]);
      mrun[jj] = mnew[jj];
      tsum[jj] = 0.f;
    }
#pragma unroll
    for (int nf = 0; nf < 4; ++nf)
#pragma unroll
      for (int jj = 0; jj < 4; ++jj) {
        float p = __expf(sa[nf][jj] - mnew[jj]);
        tsum[jj] += p;
        int row = g * 4 + jj;
        int col = nf * 16 + r;
        int pcw = (col >> 3) ^ (row & 7);
        *((__bf16*)((char*)sP[wave] + row * 128 + pcw * 16 + (col & 7) * 2)) = (__bf16)p;
      }
#pragma unroll
    for (int jj = 0; jj < 4; ++jj) {
      float ts = tsum[jj];
      ts += __shfl_xor(ts, 1);
      ts += __shfl_xor(ts, 2);
      ts += __shfl_xor(ts, 4);
      ts += __shfl_xor(ts, 8);
      lrun[jj] = lrun[jj] * scf[jj] + ts;
#pragma unroll
      for (int nf = 0; nf < 8; ++nf) o[nf][jj] *= scf[jj];
    }
    // read P as A-fragments
    bf16x8 pf[2];
#pragma unroll
    for (int k2 = 0; k2 < 2; ++k2) {
      int pc = (k2 * 4 + g) ^ (r & 7);
      pf[k2] = *(const bf16x8*)((const char*)sP[wave] + r * 128 + pc * 16);
    }
    // O += P V  (B operand from VT tile: rows = hd)
#pragma unroll
    for (int nf = 0; nf < 8; ++nf) {
#pragma unroll
      for (int k2 = 0; k2 < 2; ++k2) {
        int row = nf * 16 + r;
        int pc = (k2 * 4 + g) ^ (row & 7);
        bf16x8 vf = *(const bf16x8*)((const char*)sV + row * 128 + pc * 16);
        o[nf] = __builtin_amdgcn_mfma_f32_16x16x32_bf16(pf[k2], vf, o[nf], 0, 0, 0);
      }
    }
    __syncthreads();
  }
  // epilogue: Out (B,T,H*HD) bf16
#pragma unroll
  for (int jj = 0; jj < 4; ++jj) {
    float inv = 1.f / lrun[jj];
    int t = q0 + wave * 16 + g * 4 + jj;
#pragma unroll
    for (int nf = 0; nf < 8; ++nf) {
      int hd = nf * 16 + r;
      Out[((size_t)(b * TT + t)) * 2048 + h * 128 + hd] = (__bf16)(o[nf][jj] * inv);
    }
  }
}

// ---------------- workspace layout ----------------
constexpr size_t OFF_XB  = 0;
constexpr size_t OFF_WQT = OFF_XB + (size_t)MM * KK * 2;
constexpr size_t OFF_WKT = OFF_WQT + (size_t)NQ * KK * 2;
constexpr size_t OFF_WVT = OFF_WKT + (size_t)NK * KK * 2;
constexpr size_t OFF_WOT = OFF_WVT + (size_t)NK * KK * 2;
constexpr size_t OFF_QB  = OFF_WOT + (size_t)DD * NQ * 2;
constexpr size_t OFF_KB  = OFF_QB + (size_t)MM * NQ * 2;
constexpr size_t OFF_VTB = OFF_KB + (size_t)BB * NKV * TT * HDD * 2;
constexpr size_t OFF_ATT = OFF_VTB + (size_t)BB * NKV * TT * HDD * 2;

extern "C" void kernel_launch(void* const* d_in, const int* in_sizes, int n_in,
                              void* d_out, int out_size, void* d_ws, size_t ws_size,
                              hipStream_t stream) {
  const float* x    = (const float*)d_in[0];
  const float* fcos = (const float*)d_in[1];
  const float* fsin = (const float*)d_in[2];
  // d_in[3] = mask (unused; causal mask applied analytically)
  const float* wq = (const float*)d_in[4];
  const float* wk = (const float*)d_in[5];
  const float* wv = (const float*)d_in[6];
  const float* wo = (const float*)d_in[7];
  float* out = (float*)d_out;
  char* ws = (char*)d_ws;

  __bf16* xb   = (__bf16*)(ws + OFF_XB);
  __bf16* wqT  = (__bf16*)(ws + OFF_WQT);
  __bf16* wkT  = (__bf16*)(ws + OFF_WKT);
  __bf16* wvT  = (__bf16*)(ws + OFF_WVT);
  __bf16* woT  = (__bf16*)(ws + OFF_WOT);
  __bf16* Qb   = (__bf16*)(ws + OFF_QB);
  __bf16* Kb   = (__bf16*)(ws + OFF_KB);
  __bf16* VTb  = (__bf16*)(ws + OFF_VTB);
  __bf16* attb = (__bf16*)(ws + OFF_ATT);

  k_cvt<<<1024, 256, 0, stream>>>(x, xb, MM * KK);
  dim3 tb(32, 8);
  k_transpose_cvt<<<dim3(NQ / 32, KK / 32), tb, 0, stream>>>(wq, wqT, KK, NQ);
  k_transpose_cvt<<<dim3(NK / 32, KK / 32), tb, 0, stream>>>(wk, wkT, KK, NK);
  k_transpose_cvt<<<dim3(NK / 32, KK / 32), tb, 0, stream>>>(wv, wvT, KK, NK);
  k_transpose_cvt<<<dim3(NQ / 32, KK / 32), tb, 0, stream>>>(wo, woT, KK, NQ);

  k_gemm<EPI_ROPE_Q><<<dim3(NQ / 128, MM / 128), 256, 0, stream>>>(xb, wqT, Qb, NQ, fcos, fsin);
  k_gemm<EPI_ROPE_K><<<dim3(NK / 128, MM / 128), 256, 0, stream>>>(xb, wkT, Kb, NK, fcos, fsin);
  k_gemm<EPI_VT><<<dim3(NK / 128, MM / 128), 256, 0, stream>>>(xb, wvT, VTb, NK, nullptr, nullptr);

  k_attn<<<dim3(TT / 64, NHD, BB), 256, 0, stream>>>(Qb, Kb, VTb, attb);

  k_gemm<EPI_F32><<<dim3(NQ / 128, MM / 128), 256, 0, stream>>>(attb, woT, out, NQ, nullptr, nullptr);
}

// Round 2
// 444.983 us; speedup vs baseline: 1.0673x; 1.0673x over previous
//
#include <hip/hip_runtime.h>
#include <hip/hip_bf16.h>

// GQA attention block: x@wqkv (fused) -> RoPE -> causal GQA flash attn (paired
// q-tiles for load balance, double-buffered K/V) -> @wo
// B=2 T=2048 D=2048 H=16 HK=4 HD=128. bf16 MFMA 16x16x32, f32 accum.

constexpr int BB  = 2;
constexpr int TT  = 2048;
constexpr int DD  = 2048;
constexpr int NHD = 16;    // H
constexpr int NKV = 4;     // HK
constexpr int HDD = 128;   // HD
constexpr int MM  = BB * TT;          // 4096
constexpr int KK  = DD;               // 2048

typedef float  f32x4  __attribute__((ext_vector_type(4)));
typedef __bf16 bf16x8 __attribute__((ext_vector_type(8)));
typedef __bf16 bf16x4 __attribute__((ext_vector_type(4)));

__device__ __forceinline__ void async16(const void* g, void* l) {
  __builtin_amdgcn_global_load_lds(
      (const __attribute__((address_space(1))) unsigned int*)g,
      (__attribute__((address_space(3))) unsigned int*)l, 16, 0, 0);
}

// ---------------- elementwise f32 -> bf16 ----------------
__global__ __launch_bounds__(256) void k_cvt(const float* __restrict__ in,
                                             __bf16* __restrict__ out, int n) {
  int idx = (blockIdx.x * blockDim.x + threadIdx.x) * 4;
  int stride = gridDim.x * blockDim.x * 4;
  for (int i = idx; i < n; i += stride) {
    float4 v = *(const float4*)(in + i);
    bf16x4 o;
    o.x = (__bf16)v.x; o.y = (__bf16)v.y; o.z = (__bf16)v.z; o.w = (__bf16)v.w;
    *(bf16x4*)(out + i) = o;
  }
}

// ---------------- (K,N) f32 -> (N,K) bf16 transpose ----------------
__global__ __launch_bounds__(256) void k_transpose_cvt(const float* __restrict__ in,
                                                       __bf16* __restrict__ out,
                                                       int K, int N) {
  __shared__ float tile[32][33];
  int n0 = blockIdx.x * 32, k0 = blockIdx.y * 32;
  int tx = threadIdx.x, ty = threadIdx.y;
#pragma unroll
  for (int i = 0; i < 4; ++i)
    tile[ty + i * 8][tx] = in[(size_t)(k0 + ty + i * 8) * N + n0 + tx];
  __syncthreads();
#pragma unroll
  for (int i = 0; i < 4; ++i)
    out[(size_t)(n0 + ty + i * 8) * K + k0 + tx] = (__bf16)tile[tx][ty + i * 8];
}

// ---------------- GEMM: A(M,K) x BT(N,K), 128x128 tile, BK=64 ----------------
enum { EPI_QKV = 0, EPI_F32 = 1 };

template <int EPI>
__global__ __launch_bounds__(256, 2)
void k_gemm(const __bf16* __restrict__ A, const __bf16* __restrict__ BT,
            void* __restrict__ C0, void* __restrict__ C1, void* __restrict__ C2,
            const float* __restrict__ fcos, const float* __restrict__ fsin) {
  __shared__ __bf16 sA[128 * 64];
  __shared__ __bf16 sB[128 * 64];
  const int tid = threadIdx.x, wave = tid >> 6, lane = tid & 63;
  const int m0 = blockIdx.y * 128, n0 = blockIdx.x * 128;
  const int r = lane & 15, g = lane >> 4;
  const int wm = (wave >> 1) * 64, wn = (wave & 1) * 64;
  const int srow = lane >> 3;
  const int schunk = (lane & 7) ^ (srow & 7);

  f32x4 acc[4][4] = {};

  const __bf16* aBase = A + (size_t)m0 * KK + schunk * 8;
  const __bf16* bBase = BT + (size_t)n0 * KK + schunk * 8;

  for (int kt = 0; kt < KK; kt += 64) {
#pragma unroll
    for (int i = 0; i < 4; ++i) {
      int t = wave * 4 + i;
      int row = t * 8 + srow;
      async16(aBase + (size_t)row * KK + kt, (char*)sA + t * 1024);
      async16(bBase + (size_t)row * KK + kt, (char*)sB + t * 1024);
    }
    __syncthreads();
    bf16x8 af[4][2], bfr[4][2];
#pragma unroll
    for (int i = 0; i < 4; ++i) {
#pragma unroll
      for (int h = 0; h < 2; ++h) {
        int pc = (h * 4 + g) ^ (r & 7);
        af[i][h]  = *(const bf16x8*)((const char*)sA + (wm + i * 16 + r) * 128 + pc * 16);
        bfr[i][h] = *(const bf16x8*)((const char*)sB + (wn + i * 16 + r) * 128 + pc * 16);
      }
    }
#pragma unroll
    for (int i = 0; i < 4; ++i)
#pragma unroll
      for (int j = 0; j < 4; ++j) {
        acc[i][j] = __builtin_amdgcn_mfma_f32_16x16x32_bf16(af[i][0], bfr[j][0], acc[i][j], 0, 0, 0);
        acc[i][j] = __builtin_amdgcn_mfma_f32_16x16x32_bf16(af[i][1], bfr[j][1], acc[i][j], 0, 0, 0);
      }
    __syncthreads();
  }

#pragma unroll
  for (int i = 0; i < 4; ++i) {
#pragma unroll
    for (int j = 0; j < 4; ++j) {
#pragma unroll
      for (int jj = 0; jj < 4; ++jj) {
        int rm = m0 + wm + i * 16 + g * 4 + jj;
        int cn = n0 + wn + j * 16 + r;
        float v = acc[i][j][jj];
        if constexpr (EPI == EPI_F32) {
          ((float*)C0)[(size_t)rm * 2048 + cn] = v;
        } else {
          int b = rm >> 11, t = rm & (TT - 1);
          if (cn < 2048) {            // Q + RoPE -> (B,H,T,HD)
            int hh = cn >> 7, hd = cn & 127;
            float pv = __shfl_xor(v, 1);
            float c = fcos[t * 64 + (hd >> 1)], s = fsin[t * 64 + (hd >> 1)];
            float ov = (hd & 1) ? (pv * s + v * c) : (v * c - pv * s);
            ((__bf16*)C0)[((size_t)(b * NHD + hh) * TT + t) * HDD + hd] = (__bf16)ov;
          } else if (cn < 2560) {     // K + RoPE -> (B,HK,T,HD)
            int c2 = cn - 2048, hh = c2 >> 7, hd = c2 & 127;
            float pv = __shfl_xor(v, 1);
            float c = fcos[t * 64 + (hd >> 1)], s = fsin[t * 64 + (hd >> 1)];
            float ov = (hd & 1) ? (pv * s + v * c) : (v * c - pv * s);
            ((__bf16*)C1)[((size_t)(b * NKV + hh) * TT + t) * HDD + hd] = (__bf16)ov;
          } else {                    // V transposed -> (B,HK,HD,T)
            int c2 = cn - 2560, hh = c2 >> 7, hd = c2 & 127;
            ((__bf16*)C2)[((size_t)(b * NKV + hh) * HDD + hd) * TT + t] = (__bf16)v;
          }
        }
      }
    }
  }
}

// ---------------- flash attention tile compute ----------------
__device__ __forceinline__ void attn_tile(
    const bf16x8 qf[4], f32x4 o[8], float* mrun, float* lrun,
    const __bf16* sKb, const __bf16* sVb, __bf16* sPw,
    bool diag, int qrow0, int kv0, int r, int g) {
  f32x4 sa[4] = {};
#pragma unroll
  for (int nf = 0; nf < 4; ++nf)
#pragma unroll
    for (int kh = 0; kh < 4; ++kh) {
      int row = nf * 16 + r;
      int pc = (kh * 4 + g) ^ (row & 15);
      bf16x8 kf = *(const bf16x8*)((const char*)sKb + row * 256 + pc * 16);
      sa[nf] = __builtin_amdgcn_mfma_f32_16x16x32_bf16(qf[kh], kf, sa[nf], 0, 0, 0);
    }
  const float SC = 0.08838834764831845f; // 1/sqrt(128)
#pragma unroll
  for (int nf = 0; nf < 4; ++nf)
#pragma unroll
    for (int jj = 0; jj < 4; ++jj) {
      float s = sa[nf][jj] * SC;
      if (diag && (kv0 + nf * 16 + r > qrow0 + g * 4 + jj)) s = -1e30f;
      sa[nf][jj] = s;
    }
  float mnew[4], scf[4], tsum[4];
#pragma unroll
  for (int jj = 0; jj < 4; ++jj) {
    float mx = fmaxf(fmaxf(sa[0][jj], sa[1][jj]), fmaxf(sa[2][jj], sa[3][jj]));
    mx = fmaxf(mx, __shfl_xor(mx, 1));
    mx = fmaxf(mx, __shfl_xor(mx, 2));
    mx = fmaxf(mx, __shfl_xor(mx, 4));
    mx = fmaxf(mx, __shfl_xor(mx, 8));
    mnew[jj] = fmaxf(mrun[jj], mx);
    scf[jj] = __expf(mrun[jj] - mnew[jj]);
    mrun[jj] = mnew[jj];
    tsum[jj] = 0.f;
  }
#pragma unroll
  for (int nf = 0; nf < 4; ++nf)
#pragma unroll
    for (int jj = 0; jj < 4; ++jj) {
      float p = __expf(sa[nf][jj] - mnew[jj]);
      tsum[jj] += p;
      int row = g * 4 + jj;
      int col = nf * 16 + r;
      int pcw = (col >> 3) ^ (row & 7);
      *((__bf16*)((char*)sPw + row * 128 + pcw * 16 + (col & 7) * 2)) = (__bf16)p;
    }
#pragma unroll
  for (int jj = 0; jj < 4; ++jj) {
    float ts = tsum[jj];
    ts += __shfl_xor(ts, 1);
    ts += __shfl_xor(ts, 2);
    ts += __shfl_xor(ts, 4);
    ts += __shfl_xor(ts, 8);
    lrun[jj] = lrun[jj] * scf[jj] + ts;
#pragma unroll
    for (int nf = 0; nf < 8; ++nf) o[nf][jj] *= scf[jj];
  }
  bf16x8 pf[2];
#pragma unroll
  for (int k2 = 0; k2 < 2; ++k2) {
    int pc = (k2 * 4 + g) ^ (r & 7);
    pf[k2] = *(const bf16x8*)((const char*)sPw + r * 128 + pc * 16);
  }
#pragma unroll
  for (int nf = 0; nf < 8; ++nf)
#pragma unroll
    for (int k2 = 0; k2 < 2; ++k2) {
      int row = nf * 16 + r;
      int pc = (k2 * 4 + g) ^ (row & 7);
      bf16x8 vf = *(const bf16x8*)((const char*)sVb + row * 128 + pc * 16);
      o[nf] = __builtin_amdgcn_mfma_f32_16x16x32_bf16(pf[k2], vf, o[nf], 0, 0, 0);
    }
}

// ---------------- flash attention ----------------
// grid (16 pairs, H, B), 256 thr = 4 waves. Block handles q-tile pair
// (pa, 31-pa): uniform 33 compute-tile-units/block; K/V staged once per pair.
// Double-buffered K/V (2-phase prefetch).
__global__ __launch_bounds__(256, 2)
void k_attn(const __bf16* __restrict__ Q, const __bf16* __restrict__ Kc,
            const __bf16* __restrict__ VT, __bf16* __restrict__ Out) {
  __shared__ __bf16 sK[2][64 * 128];   // 32 KB
  __shared__ __bf16 sV[2][128 * 64];   // 32 KB
  __shared__ __bf16 sP[4][16 * 64];    //  8 KB  (shared between A/B, same-wave order)

  const int tid = threadIdx.x, wave = tid >> 6, lane = tid & 63;
  const int pa = blockIdx.x;                   // 0..15
  const int tileA = pa, tileB = 31 - pa;
  const int qa0 = tileA * 64, qb0 = tileB * 64;
  const int h = blockIdx.y, b = blockIdx.z;
  const int kvh = h >> 2;
  const int r = lane & 15, g = lane >> 4;

  const __bf16* Qp = Q + ((size_t)(b * NHD + h) * TT) * HDD;
  const __bf16* Kp = Kc + ((size_t)(b * NKV + kvh) * TT) * HDD;
  const __bf16* Vp = VT + ((size_t)(b * NKV + kvh) * HDD) * TT;

  bf16x8 qfA[4], qfB[4];
#pragma unroll
  for (int kh = 0; kh < 4; ++kh) {
    qfA[kh] = *(const bf16x8*)(Qp + (size_t)(qa0 + wave * 16 + r) * HDD + kh * 32 + g * 8);
    qfB[kh] = *(const bf16x8*)(Qp + (size_t)(qb0 + wave * 16 + r) * HDD + kh * 32 + g * 8);
  }

  f32x4 oA[8] = {}, oB[8] = {};
  float mA[4], lA[4], mB[4], lB[4];
#pragma unroll
  for (int jj = 0; jj < 4; ++jj) {
    mA[jj] = -1e30f; lA[jj] = 0.f; mB[jj] = -1e30f; lB[jj] = 0.f;
  }

  auto stage = [&](int kv0, int buf) {
#pragma unroll
    for (int i = 0; i < 4; ++i) {
      int ti = wave * 4 + i;
      int rowk = ti * 4 + (lane >> 4);
      int sck = (lane & 15) ^ (rowk & 15);
      async16(Kp + (size_t)(kv0 + rowk) * HDD + sck * 8, (char*)sK[buf] + ti * 1024);
      int rowv = ti * 8 + (lane >> 3);
      int scv = (lane & 7) ^ (rowv & 7);
      async16(Vp + (size_t)rowv * TT + kv0 + scv * 8, (char*)sV[buf] + ti * 1024);
    }
  };

  stage(0, 0);
  const int nt = tileB + 1;
  for (int it = 0; it < nt; ++it) {
    const int cur = it & 1;
    const int kv0 = it * 64;
    __syncthreads();                       // drains stage(it); fences buf reuse
    if (it + 1 < nt) stage(kv0 + 64, cur ^ 1);

    attn_tile(qfB, oB, mB, lB, sK[cur], sV[cur], sP[wave],
              it == tileB, qb0 + wave * 16, kv0, r, g);
    if (it <= tileA)
      attn_tile(qfA, oA, mA, lA, sK[cur], sV[cur], sP[wave],
                it == tileA, qa0 + wave * 16, kv0, r, g);
  }

  // epilogue: Out (B,T,H*HD) bf16 for both q-tiles
#pragma unroll
  for (int jj = 0; jj < 4; ++jj) {
    float invB = 1.f / lB[jj];
    int tb2 = qb0 + wave * 16 + g * 4 + jj;
    float invA = 1.f / lA[jj];
    int ta2 = qa0 + wave * 16 + g * 4 + jj;
#pragma unroll
    for (int nf = 0; nf < 8; ++nf) {
      int hd = nf * 16 + r;
      Out[((size_t)(b * TT + tb2)) * 2048 + h * 128 + hd] = (__bf16)(oB[nf][jj] * invB);
      Out[((size_t)(b * TT + ta2)) * 2048 + h * 128 + hd] = (__bf16)(oA[nf][jj] * invA);
    }
  }
}

// ---------------- workspace layout ----------------
constexpr size_t OFF_XB   = 0;
constexpr size_t OFF_WQKV = OFF_XB + (size_t)MM * KK * 2;                 // x bf16
constexpr size_t OFF_WOT  = OFF_WQKV + (size_t)3072 * KK * 2;             // wqkv^T
constexpr size_t OFF_QB   = OFF_WOT + (size_t)2048 * KK * 2;              // wo^T
constexpr size_t OFF_KB   = OFF_QB + (size_t)MM * 2048 * 2;
constexpr size_t OFF_VTB  = OFF_KB + (size_t)BB * NKV * TT * HDD * 2;
constexpr size_t OFF_ATT  = OFF_VTB + (size_t)BB * NKV * TT * HDD * 2;

extern "C" void kernel_launch(void* const* d_in, const int* in_sizes, int n_in,
                              void* d_out, int out_size, void* d_ws, size_t ws_size,
                              hipStream_t stream) {
  const float* x    = (const float*)d_in[0];
  const float* fcos = (const float*)d_in[1];
  const float* fsin = (const float*)d_in[2];
  // d_in[3] = mask (unused; causal applied analytically)
  const float* wq = (const float*)d_in[4];
  const float* wk = (const float*)d_in[5];
  const float* wv = (const float*)d_in[6];
  const float* wo = (const float*)d_in[7];
  float* out = (float*)d_out;
  char* ws = (char*)d_ws;

  __bf16* xb    = (__bf16*)(ws + OFF_XB);
  __bf16* wqkvT = (__bf16*)(ws + OFF_WQKV);
  __bf16* woT   = (__bf16*)(ws + OFF_WOT);
  __bf16* Qb    = (__bf16*)(ws + OFF_QB);
  __bf16* Kb    = (__bf16*)(ws + OFF_KB);
  __bf16* VTb   = (__bf16*)(ws + OFF_VTB);
  __bf16* attb  = (__bf16*)(ws + OFF_ATT);

  k_cvt<<<1024, 256, 0, stream>>>(x, xb, MM * KK);
  dim3 tb(32, 8);
  k_transpose_cvt<<<dim3(2048 / 32, KK / 32), tb, 0, stream>>>(wq, wqkvT, KK, 2048);
  k_transpose_cvt<<<dim3(512 / 32, KK / 32), tb, 0, stream>>>(wk, wqkvT + (size_t)2048 * KK, KK, 512);
  k_transpose_cvt<<<dim3(512 / 32, KK / 32), tb, 0, stream>>>(wv, wqkvT + (size_t)2560 * KK, KK, 512);
  k_transpose_cvt<<<dim3(2048 / 32, KK / 32), tb, 0, stream>>>(wo, woT, KK, 2048);

  k_gemm<EPI_QKV><<<dim3(3072 / 128, MM / 128), 256, 0, stream>>>(
      xb, wqkvT, Qb, Kb, VTb, fcos, fsin);

  k_attn<<<dim3(16, NHD, BB), 256, 0, stream>>>(Qb, Kb, VTb, attb);

  k_gemm<EPI_F32><<<dim3(2048 / 128, MM / 128), 256, 0, stream>>>(
      attb, woT, out, nullptr, nullptr, nullptr, nullptr);
}

// Round 4
// 330.876 us; speedup vs baseline: 1.4353x; 1.3449x over previous
//
#include <hip/hip_runtime.h>
#include <hip/hip_bf16.h>

// GQA attention block: x@wqkv (fused) -> RoPE -> causal GQA flash attn (paired
// q-tiles processed SEQUENTIALLY per block for load balance without register
// blowup, double-buffered K/V) -> @wo
// B=2 T=2048 D=2048 H=16 HK=4 HD=128. bf16 MFMA 16x16x32, f32 accum.

constexpr int BB  = 2;
constexpr int TT  = 2048;
constexpr int DD  = 2048;
constexpr int NHD = 16;    // H
constexpr int NKV = 4;     // HK
constexpr int HDD = 128;   // HD
constexpr int MM  = BB * TT;          // 4096
constexpr int KK  = DD;               // 2048

typedef float  f32x4  __attribute__((ext_vector_type(4)));
typedef __bf16 bf16x8 __attribute__((ext_vector_type(8)));
typedef __bf16 bf16x4 __attribute__((ext_vector_type(4)));

__device__ __forceinline__ void async16(const void* g, void* l) {
  __builtin_amdgcn_global_load_lds(
      (const __attribute__((address_space(1))) unsigned int*)g,
      (__attribute__((address_space(3))) unsigned int*)l, 16, 0, 0);
}

// ---------------- elementwise f32 -> bf16 ----------------
__global__ __launch_bounds__(256) void k_cvt(const float* __restrict__ in,
                                             __bf16* __restrict__ out, int n) {
  int idx = (blockIdx.x * blockDim.x + threadIdx.x) * 4;
  int stride = gridDim.x * blockDim.x * 4;
  for (int i = idx; i < n; i += stride) {
    float4 v = *(const float4*)(in + i);
    bf16x4 o;
    o.x = (__bf16)v.x; o.y = (__bf16)v.y; o.z = (__bf16)v.z; o.w = (__bf16)v.w;
    *(bf16x4*)(out + i) = o;
  }
}

// ---------------- (K,N) f32 -> (N,K) bf16 transpose ----------------
__global__ __launch_bounds__(256) void k_transpose_cvt(const float* __restrict__ in,
                                                       __bf16* __restrict__ out,
                                                       int K, int N) {
  __shared__ float tile[32][33];
  int n0 = blockIdx.x * 32, k0 = blockIdx.y * 32;
  int tx = threadIdx.x, ty = threadIdx.y;
#pragma unroll
  for (int i = 0; i < 4; ++i)
    tile[ty + i * 8][tx] = in[(size_t)(k0 + ty + i * 8) * N + n0 + tx];
  __syncthreads();
#pragma unroll
  for (int i = 0; i < 4; ++i)
    out[(size_t)(n0 + ty + i * 8) * K + k0 + tx] = (__bf16)tile[tx][ty + i * 8];
}

// ---------------- GEMM: A(M,K) x BT(N,K), 128x128 tile, BK=64 ----------------
enum { EPI_QKV = 0, EPI_F32 = 1 };

template <int EPI>
__global__ __launch_bounds__(256, 2)
void k_gemm(const __bf16* __restrict__ A, const __bf16* __restrict__ BT,
            void* __restrict__ C0, void* __restrict__ C1, void* __restrict__ C2,
            const float* __restrict__ fcos, const float* __restrict__ fsin) {
  __shared__ __bf16 sA[128 * 64];
  __shared__ __bf16 sB[128 * 64];
  const int tid = threadIdx.x, wave = tid >> 6, lane = tid & 63;
  const int m0 = blockIdx.y * 128, n0 = blockIdx.x * 128;
  const int r = lane & 15, g = lane >> 4;
  const int wm = (wave >> 1) * 64, wn = (wave & 1) * 64;
  const int srow = lane >> 3;
  const int schunk = (lane & 7) ^ (srow & 7);

  f32x4 acc[4][4] = {};

  const __bf16* aBase = A + (size_t)m0 * KK + schunk * 8;
  const __bf16* bBase = BT + (size_t)n0 * KK + schunk * 8;

  for (int kt = 0; kt < KK; kt += 64) {
#pragma unroll
    for (int i = 0; i < 4; ++i) {
      int t = wave * 4 + i;
      int row = t * 8 + srow;
      async16(aBase + (size_t)row * KK + kt, (char*)sA + t * 1024);
      async16(bBase + (size_t)row * KK + kt, (char*)sB + t * 1024);
    }
    __syncthreads();
    bf16x8 af[4][2], bfr[4][2];
#pragma unroll
    for (int i = 0; i < 4; ++i) {
#pragma unroll
      for (int h = 0; h < 2; ++h) {
        int pc = (h * 4 + g) ^ (r & 7);
        af[i][h]  = *(const bf16x8*)((const char*)sA + (wm + i * 16 + r) * 128 + pc * 16);
        bfr[i][h] = *(const bf16x8*)((const char*)sB + (wn + i * 16 + r) * 128 + pc * 16);
      }
    }
#pragma unroll
    for (int i = 0; i < 4; ++i)
#pragma unroll
      for (int j = 0; j < 4; ++j) {
        acc[i][j] = __builtin_amdgcn_mfma_f32_16x16x32_bf16(af[i][0], bfr[j][0], acc[i][j], 0, 0, 0);
        acc[i][j] = __builtin_amdgcn_mfma_f32_16x16x32_bf16(af[i][1], bfr[j][1], acc[i][j], 0, 0, 0);
      }
    __syncthreads();
  }

#pragma unroll
  for (int i = 0; i < 4; ++i) {
#pragma unroll
    for (int j = 0; j < 4; ++j) {
#pragma unroll
      for (int jj = 0; jj < 4; ++jj) {
        int rm = m0 + wm + i * 16 + g * 4 + jj;
        int cn = n0 + wn + j * 16 + r;
        float v = acc[i][j][jj];
        if constexpr (EPI == EPI_F32) {
          ((float*)C0)[(size_t)rm * 2048 + cn] = v;
        } else {
          int b = rm >> 11, t = rm & (TT - 1);
          if (cn < 2048) {            // Q + RoPE -> (B,H,T,HD)
            int hh = cn >> 7, hd = cn & 127;
            float pv = __shfl_xor(v, 1);
            float c = fcos[t * 64 + (hd >> 1)], s = fsin[t * 64 + (hd >> 1)];
            float ov = (hd & 1) ? (pv * s + v * c) : (v * c - pv * s);
            ((__bf16*)C0)[((size_t)(b * NHD + hh) * TT + t) * HDD + hd] = (__bf16)ov;
          } else if (cn < 2560) {     // K + RoPE -> (B,HK,T,HD)
            int c2 = cn - 2048, hh = c2 >> 7, hd = c2 & 127;
            float pv = __shfl_xor(v, 1);
            float c = fcos[t * 64 + (hd >> 1)], s = fsin[t * 64 + (hd >> 1)];
            float ov = (hd & 1) ? (pv * s + v * c) : (v * c - pv * s);
            ((__bf16*)C1)[((size_t)(b * NKV + hh) * TT + t) * HDD + hd] = (__bf16)ov;
          } else {                    // V transposed -> (B,HK,HD,T)
            int c2 = cn - 2560, hh = c2 >> 7, hd = c2 & 127;
            ((__bf16*)C2)[((size_t)(b * NKV + hh) * HDD + hd) * TT + t] = (__bf16)v;
          }
        }
      }
    }
  }
}

// ---------------- flash attention tile compute ----------------
__device__ __forceinline__ void attn_tile(
    const bf16x8 qf[4], f32x4 o[8], float* mrun, float* lrun,
    const __bf16* sKb, const __bf16* sVb, __bf16* sPw,
    bool diag, int qrow0, int kv0, int r, int g) {
  f32x4 sa[4] = {};
#pragma unroll
  for (int nf = 0; nf < 4; ++nf)
#pragma unroll
    for (int kh = 0; kh < 4; ++kh) {
      int row = nf * 16 + r;
      int pc = (kh * 4 + g) ^ (row & 15);
      bf16x8 kf = *(const bf16x8*)((const char*)sKb + row * 256 + pc * 16);
      sa[nf] = __builtin_amdgcn_mfma_f32_16x16x32_bf16(qf[kh], kf, sa[nf], 0, 0, 0);
    }
  const float SC = 0.08838834764831845f; // 1/sqrt(128)
#pragma unroll
  for (int nf = 0; nf < 4; ++nf)
#pragma unroll
    for (int jj = 0; jj < 4; ++jj) {
      float s = sa[nf][jj] * SC;
      if (diag && (kv0 + nf * 16 + r > qrow0 + g * 4 + jj)) s = -1e30f;
      sa[nf][jj] = s;
    }
  float mnew[4], scf[4], tsum[4];
#pragma unroll
  for (int jj = 0; jj < 4; ++jj) {
    float mx = fmaxf(fmaxf(sa[0][jj], sa[1][jj]), fmaxf(sa[2][jj], sa[3][jj]));
    mx = fmaxf(mx, __shfl_xor(mx, 1));
    mx = fmaxf(mx, __shfl_xor(mx, 2));
    mx = fmaxf(mx, __shfl_xor(mx, 4));
    mx = fmaxf(mx, __shfl_xor(mx, 8));
    mnew[jj] = fmaxf(mrun[jj], mx);
    scf[jj] = __expf(mrun[jj] - mnew[jj]);
    mrun[jj] = mnew[jj];
    tsum[jj] = 0.f;
  }
#pragma unroll
  for (int nf = 0; nf < 4; ++nf)
#pragma unroll
    for (int jj = 0; jj < 4; ++jj) {
      float p = __expf(sa[nf][jj] - mnew[jj]);
      tsum[jj] += p;
      int row = g * 4 + jj;
      int col = nf * 16 + r;
      int pcw = (col >> 3) ^ (row & 7);
      *((__bf16*)((char*)sPw + row * 128 + pcw * 16 + (col & 7) * 2)) = (__bf16)p;
    }
#pragma unroll
  for (int jj = 0; jj < 4; ++jj) {
    float ts = tsum[jj];
    ts += __shfl_xor(ts, 1);
    ts += __shfl_xor(ts, 2);
    ts += __shfl_xor(ts, 4);
    ts += __shfl_xor(ts, 8);
    lrun[jj] = lrun[jj] * scf[jj] + ts;
#pragma unroll
    for (int nf = 0; nf < 8; ++nf) o[nf][jj] *= scf[jj];
  }
  bf16x8 pf[2];
#pragma unroll
  for (int k2 = 0; k2 < 2; ++k2) {
    int pc = (k2 * 4 + g) ^ (r & 7);
    pf[k2] = *(const bf16x8*)((const char*)sPw + r * 128 + pc * 16);
  }
#pragma unroll
  for (int nf = 0; nf < 8; ++nf)
#pragma unroll
    for (int k2 = 0; k2 < 2; ++k2) {
      int row = nf * 16 + r;
      int pc = (k2 * 4 + g) ^ (row & 7);
      bf16x8 vf = *(const bf16x8*)((const char*)sVb + row * 128 + pc * 16);
      o[nf] = __builtin_amdgcn_mfma_f32_16x16x32_bf16(pf[k2], vf, o[nf], 0, 0, 0);
    }
}

// ---------------- flash attention ----------------
// grid (16 pairs, H, B), 256 thr = 4 waves. Block handles q-tile pair
// (pa, 31-pa) SEQUENTIALLY: uniform 33 tile-units/block, single live o/m/l/qf
// register set (no spill). K/V double-buffered via global_load_lds.
__global__ __launch_bounds__(256, 2)
void k_attn(const __bf16* __restrict__ Q, const __bf16* __restrict__ Kc,
            const __bf16* __restrict__ VT, __bf16* __restrict__ Out) {
  __shared__ __bf16 sK[2][64 * 128];   // 32 KB
  __shared__ __bf16 sV[2][128 * 64];   // 32 KB
  __shared__ __bf16 sP[4][16 * 64];    //  8 KB

  const int tid = threadIdx.x, wave = tid >> 6, lane = tid & 63;
  const int pa = blockIdx.x;                   // 0..15
  const int h = blockIdx.y, b = blockIdx.z;
  const int kvh = h >> 2;
  const int r = lane & 15, g = lane >> 4;

  const __bf16* Qp = Q + ((size_t)(b * NHD + h) * TT) * HDD;
  const __bf16* Kp = Kc + ((size_t)(b * NKV + kvh) * TT) * HDD;
  const __bf16* Vp = VT + ((size_t)(b * NKV + kvh) * HDD) * TT;

  auto stage = [&](int kv0, int buf) {
#pragma unroll
    for (int i = 0; i < 4; ++i) {
      int ti = wave * 4 + i;
      int rowk = ti * 4 + (lane >> 4);
      int sck = (lane & 15) ^ (rowk & 15);
      async16(Kp + (size_t)(kv0 + rowk) * HDD + sck * 8, (char*)sK[buf] + ti * 1024);
      int rowv = ti * 8 + (lane >> 3);
      int scv = (lane & 7) ^ (rowv & 7);
      async16(Vp + (size_t)rowv * TT + kv0 + scv * 8, (char*)sV[buf] + ti * 1024);
    }
  };

  auto run_qtile = [&](int qt) {
    const int q00 = qt * 64;
    bf16x8 qf[4];
#pragma unroll
    for (int kh = 0; kh < 4; ++kh)
      qf[kh] = *(const bf16x8*)(Qp + (size_t)(q00 + wave * 16 + r) * HDD + kh * 32 + g * 8);
    f32x4 o[8] = {};
    float m[4], l[4];
#pragma unroll
    for (int jj = 0; jj < 4; ++jj) { m[jj] = -1e30f; l[jj] = 0.f; }

    __syncthreads();             // prior phase done reading buffers
    stage(0, 0);
    for (int it = 0; it <= qt; ++it) {
      __syncthreads();           // drains stage(it); fences buffer reuse
      if (it < qt) stage((it + 1) * 64, (it + 1) & 1);
      attn_tile(qf, o, m, l, sK[it & 1], sV[it & 1], sP[wave],
                it == qt, q00 + wave * 16, it * 64, r, g);
    }
    // epilogue: Out (B,T,H*HD) bf16
#pragma unroll
    for (int jj = 0; jj < 4; ++jj) {
      float inv = 1.f / l[jj];
      int t = q00 + wave * 16 + g * 4 + jj;
#pragma unroll
      for (int nf = 0; nf < 8; ++nf) {
        int hd = nf * 16 + r;
        Out[((size_t)(b * TT + t)) * 2048 + h * 128 + hd] = (__bf16)(o[nf][jj] * inv);
      }
    }
  };

  run_qtile(31 - pa);   // long tile first
  run_qtile(pa);        // short tile
}

// ---------------- workspace layout ----------------
constexpr size_t OFF_XB   = 0;
constexpr size_t OFF_WQKV = OFF_XB + (size_t)MM * KK * 2;                 // x bf16
constexpr size_t OFF_WOT  = OFF_WQKV + (size_t)3072 * KK * 2;             // wqkv^T
constexpr size_t OFF_QB   = OFF_WOT + (size_t)2048 * KK * 2;              // wo^T
constexpr size_t OFF_KB   = OFF_QB + (size_t)MM * 2048 * 2;
constexpr size_t OFF_VTB  = OFF_KB + (size_t)BB * NKV * TT * HDD * 2;
constexpr size_t OFF_ATT  = OFF_VTB + (size_t)BB * NKV * TT * HDD * 2;

extern "C" void kernel_launch(void* const* d_in, const int* in_sizes, int n_in,
                              void* d_out, int out_size, void* d_ws, size_t ws_size,
                              hipStream_t stream) {
  const float* x    = (const float*)d_in[0];
  const float* fcos = (const float*)d_in[1];
  const float* fsin = (const float*)d_in[2];
  // d_in[3] = mask (unused; causal applied analytically)
  const float* wq = (const float*)d_in[4];
  const float* wk = (const float*)d_in[5];
  const float* wv = (const float*)d_in[6];
  const float* wo = (const float*)d_in[7];
  float* out = (float*)d_out;
  char* ws = (char*)d_ws;

  __bf16* xb    = (__bf16*)(ws + OFF_XB);
  __bf16* wqkvT = (__bf16*)(ws + OFF_WQKV);
  __bf16* woT   = (__bf16*)(ws + OFF_WOT);
  __bf16* Qb    = (__bf16*)(ws + OFF_QB);
  __bf16* Kb    = (__bf16*)(ws + OFF_KB);
  __bf16* VTb   = (__bf16*)(ws + OFF_VTB);
  __bf16* attb  = (__bf16*)(ws + OFF_ATT);

  k_cvt<<<1024, 256, 0, stream>>>(x, xb, MM * KK);
  dim3 tb(32, 8);
  k_transpose_cvt<<<dim3(2048 / 32, KK / 32), tb, 0, stream>>>(wq, wqkvT, KK, 2048);
  k_transpose_cvt<<<dim3(512 / 32, KK / 32), tb, 0, stream>>>(wk, wqkvT + (size_t)2048 * KK, KK, 512);
  k_transpose_cvt<<<dim3(512 / 32, KK / 32), tb, 0, stream>>>(wv, wqkvT + (size_t)2560 * KK, KK, 512);
  k_transpose_cvt<<<dim3(2048 / 32, KK / 32), tb, 0, stream>>>(wo, woT, KK, 2048);

  k_gemm<EPI_QKV><<<dim3(3072 / 128, MM / 128), 256, 0, stream>>>(
      xb, wqkvT, Qb, Kb, VTb, fcos, fsin);

  k_attn<<<dim3(16, NHD, BB), 256, 0, stream>>>(Qb, Kb, VTb, attb);

  k_gemm<EPI_F32><<<dim3(2048 / 128, MM / 128), 256, 0, stream>>>(
      attb, woT, out, nullptr, nullptr, nullptr, nullptr);
}